// Round 4
// baseline (124.164 us; speedup 1.0000x reference)
//
#include <hip/hip_runtime.h>
#include <hip/hip_bf16.h>

// Problem constants (from reference)
#define T_LEN 2048
#define D_DIM 64
#define K_CH  8
#define B_SZ  8

// Chunked-scan config
#define CT 32                  // timesteps per chunk
#define NC (T_LEN / CT)        // 64 chunks per batch
#define NBLK (B_SZ * NC)       // 512 blocks = 2 blocks/CU -> all co-resident

__device__ __forceinline__ float2 cmul(float2 a, float2 b) {
    return make_float2(a.x * b.x - a.y * b.y, a.x * b.y + a.y * b.x);
}
__device__ __forceinline__ float2 cadd(float2 a, float2 b) {
    return make_float2(a.x + b.x, a.y + b.y);
}

// Single-pass fused chunked scan.
// Block bc=(b,c): 512 threads = 8 k-waves x 64 d-lanes.
//  1. load h chunk (CT x 256B coalesced) into registers
//  2. chunk aggregate S = sum_t A^{CT-1-t} h_t   (even/odd split chains)
//  3. publish S to agg[bc], release flag[bc]
//  4. spin on flags[b,0..c-1] (all blocks co-resident -> near-zero wait),
//     combine aggregates (grouped by 4) into x_init
//  5. replay chunk from registers, out[b,t,k,d] = 2*Re(C*x_t), coalesced stores
__global__ __launch_bounds__(512, 4) void s4d_fused(
    const float* __restrict__ h,
    const float* __restrict__ log_neg_re,
    const float* __restrict__ imag,
    const float* __restrict__ B_proj,
    const float* __restrict__ log_dt,
    float2* __restrict__ agg,      // [NBLK][K_CH*D_DIM]
    int* __restrict__ flags,       // [NBLK], memset to 0 each launch
    float* __restrict__ out)
{
    const int bc = blockIdx.x;
    const int b = bc / NC;
    const int c = bc % NC;
    const int tid = threadIdx.x;     // 0..511
    const int k = tid >> 6;          // wave-uniform
    const int lane = tid & 63;       // = d

    // --- per-k constants (closed form, matches reference) ---
    const float dt = expf(log_dt[0]);
    const float re = -expf(log_neg_re[k]);
    const float im = imag[k];
    const float mag = expf(re * dt);
    const float2 A = make_float2(mag * cosf(im * dt), mag * sinf(im * dt));
    const float2 A2 = cmul(A, A);

    const float magC = expf(re * dt * (float)CT);
    const float angC = im * dt * (float)CT;
    const float2 Act  = make_float2(magC * cosf(angC), magC * sinf(angC));
    const float2 Act2 = cmul(Act, Act);
    const float2 Act3 = cmul(Act2, Act);
    const float2 Act4 = cmul(Act2, Act2);

    // C2 = 2 * B_proj * (A-1)/eig
    const float inv = 1.f / (re * re + im * im);
    const float2 num = make_float2(A.x - 1.f, A.y);
    const float bp = B_proj[k];
    const float2 C2v = make_float2(2.f * bp * (num.x * re + num.y * im) * inv,
                                   2.f * bp * (num.y * re - num.x * im) * inv);

    // --- 1. load chunk into registers (reused for aggregate AND replay) ---
    const float* hp = h + ((size_t)b * T_LEN + (size_t)c * CT) * D_DIM + lane;
    float hv[CT];
    #pragma unroll
    for (int t = 0; t < CT; ++t) hv[t] = hp[(size_t)t * D_DIM];

    // --- 2. chunk aggregate, even/odd split (two independent chains, step A2)
    // S = A*se + so where se = sum_m (A2)^{CT/2-1-m} h_{2m},
    //                     so = sum_m (A2)^{CT/2-1-m} h_{2m+1}
    float2 se = make_float2(0.f, 0.f), so = make_float2(0.f, 0.f);
    #pragma unroll
    for (int m = 0; m < CT / 2; ++m) {
        se = cmul(A2, se); se.x += hv[2 * m];
        so = cmul(A2, so); so.x += hv[2 * m + 1];
    }
    const float2 S = cadd(cmul(A, se), so);

    // --- 3. publish aggregate + release flag ---
    agg[(size_t)bc * (K_CH * D_DIM) + tid] = S;
    __syncthreads();   // drains vmcnt: all block stores are in L2
    if (tid == 0) {
        __threadfence();  // agent fence: L2 writeback -> coherence point
        __hip_atomic_store(&flags[bc], 1, __ATOMIC_RELEASE, __HIP_MEMORY_SCOPE_AGENT);
    }

    // --- 4. wait for predecessors & combine their aggregates ---
    float2 x = make_float2(0.f, 0.f);
    if (c > 0) {
        const int base = b * NC;
        if (lane < c) {
            while (__hip_atomic_load(&flags[base + lane], __ATOMIC_RELAXED,
                                     __HIP_MEMORY_SCOPE_AGENT) == 0) { }
        }
        __threadfence();  // acquire side: invalidate stale cache before agg reads

        const float2* cp = agg + (size_t)base * (K_CH * D_DIM) + tid;
        const size_t cstride = (size_t)K_CH * D_DIM;
        int j = 0;
        for (; j + 4 <= c; j += 4) {
            float2 s0 = cp[(size_t)(j + 0) * cstride];
            float2 s1 = cp[(size_t)(j + 1) * cstride];
            float2 s2 = cp[(size_t)(j + 2) * cstride];
            float2 s3 = cp[(size_t)(j + 3) * cstride];
            float2 t01 = cadd(cmul(Act3, s0), cmul(Act2, s1));
            float2 t23 = cadd(cmul(Act, s2), s3);
            x = cadd(cmul(Act4, x), cadd(t01, t23));
        }
        for (; j < c; ++j) {
            float2 s = cp[(size_t)j * cstride];
            x = cadd(cmul(Act, x), s);
        }
    }

    // --- 5. replay chunk from registers, write output ---
    float* op = out + (((size_t)b * T_LEN + (size_t)c * CT) * K_CH + k) * D_DIM + lane;
    #pragma unroll
    for (int t = 0; t < CT; ++t) {
        x = cmul(A, x);
        x.x += hv[t];
        op[(size_t)t * (K_CH * D_DIM)] = C2v.x * x.x - C2v.y * x.y;  // 256B/wave coalesced
    }
}

extern "C" void kernel_launch(void* const* d_in, const int* in_sizes, int n_in,
                              void* d_out, int out_size, void* d_ws, size_t ws_size,
                              hipStream_t stream) {
    const float* h          = (const float*)d_in[0];
    const float* log_neg_re = (const float*)d_in[1];
    const float* imag       = (const float*)d_in[2];
    const float* B_proj     = (const float*)d_in[3];
    const float* log_dt     = (const float*)d_in[4];
    float* out = (float*)d_out;

    // d_ws layout: [0,2KB) flags, [8KB, 8KB+2MB) aggregates
    int*    flags = (int*)d_ws;
    float2* agg   = (float2*)((char*)d_ws + 8192);

    // Flags must be zero at kernel start each call (d_ws is NOT re-poisoned
    // between replays). hipMemsetAsync is graph-capture-safe.
    hipMemsetAsync(flags, 0, NBLK * sizeof(int), stream);

    hipLaunchKernelGGL(s4d_fused, dim3(NBLK), dim3(512), 0, stream,
                       h, log_neg_re, imag, B_proj, log_dt, agg, flags, out);
}

// Round 5
// 25.421 us; speedup vs baseline: 4.8843x; 4.8843x over previous
//
#include <hip/hip_runtime.h>
#include <hip/hip_bf16.h>

// Problem constants (from reference)
#define T_LEN 2048
#define D_DIM 64
#define K_CH  8
#define B_SZ  8

// Chunked-scan config
#define CT 32                 // timesteps per chunk
#define NC (T_LEN / CT)       // 64 chunks
#define NBLK (B_SZ * NC)      // 512 blocks

__device__ __forceinline__ float2 cmul(float2 a, float2 b) {
    return make_float2(a.x * b.x - a.y * b.y, a.x * b.y + a.y * b.x);
}
__device__ __forceinline__ float2 cadd(float2 a, float2 b) {
    return make_float2(a.x + b.x, a.y + b.y);
}

// Thread decomposition (both kernels): block=256, tid -> (k = tid>>5, d2 = tid&31),
// each thread owns d = 2*d2 and 2*d2+1  => float2 h loads (8B/lane),
// float4 carry traffic (16B/lane), float2 out stores (8B/lane).

// Kernel 1: chunk-local aggregate S = sum_j A^{CT-1-j} h[j], zero init.
// Even/odd split -> 4 independent cmul chains (ILP).
__global__ __launch_bounds__(256) void s4d_carry(
    const float* __restrict__ h,
    const float* __restrict__ log_neg_re,
    const float* __restrict__ imag,
    const float* __restrict__ log_dt,
    float4* __restrict__ carries)   // [NBLK][256] float4 = (S_d.re,S_d.im,S_d1.re,S_d1.im)
{
    const int bc = blockIdx.x;
    const int b = bc / NC;
    const int c = bc % NC;
    const int tid = threadIdx.x;    // 0..255
    const int k = tid >> 5;
    const int d2 = tid & 31;

    const float dt = expf(log_dt[0]);
    const float re = -expf(log_neg_re[k]);
    const float im = imag[k];
    const float mag = expf(re * dt);
    const float2 A = make_float2(mag * cosf(im * dt), mag * sinf(im * dt));
    const float2 A2 = cmul(A, A);

    const float2* hp = (const float2*)(h + ((size_t)b * T_LEN + (size_t)c * CT) * D_DIM) + d2;

    float2 x0e = {0.f, 0.f}, x0o = {0.f, 0.f}, x1e = {0.f, 0.f}, x1o = {0.f, 0.f};
    #pragma unroll
    for (int m = 0; m < CT / 2; ++m) {
        float2 he = hp[(size_t)(2 * m) * (D_DIM / 2)];       // 8B/lane coalesced
        float2 ho = hp[(size_t)(2 * m + 1) * (D_DIM / 2)];
        x0e = cmul(A2, x0e); x0e.x += he.x;
        x1e = cmul(A2, x1e); x1e.x += he.y;
        x0o = cmul(A2, x0o); x0o.x += ho.x;
        x1o = cmul(A2, x1o); x1o.x += ho.y;
    }
    const float2 S0 = cadd(cmul(A, x0e), x0o);
    const float2 S1 = cadd(cmul(A, x1e), x1o);

    carries[(size_t)bc * 256 + tid] = make_float4(S0.x, S0.y, S1.x, S1.y);  // 16B/lane
}

// Kernel 2: combine predecessor aggregates (grouped by 4), replay chunk, write out.
__global__ __launch_bounds__(256) void s4d_out(
    const float* __restrict__ h,
    const float* __restrict__ log_neg_re,
    const float* __restrict__ imag,
    const float* __restrict__ B_proj,
    const float* __restrict__ log_dt,
    const float4* __restrict__ carries,
    float* __restrict__ out)
{
    const int bc = blockIdx.x;
    const int b = bc / NC;
    const int c = bc % NC;
    const int tid = threadIdx.x;
    const int k = tid >> 5;
    const int d2 = tid & 31;

    const float dt = expf(log_dt[0]);
    const float re = -expf(log_neg_re[k]);
    const float im = imag[k];
    const float mag = expf(re * dt);
    const float2 A = make_float2(mag * cosf(im * dt), mag * sinf(im * dt));

    const float magC = expf(re * dt * (float)CT);
    const float angC = im * dt * (float)CT;
    const float2 Act  = make_float2(magC * cosf(angC), magC * sinf(angC));
    const float2 Act2 = cmul(Act, Act);
    const float2 Act3 = cmul(Act2, Act);
    const float2 Act4 = cmul(Act2, Act2);

    // C2 = 2 * B_proj * (A-1)/eig
    const float inv = 1.f / (re * re + im * im);
    const float2 num = make_float2(A.x - 1.f, A.y);
    const float bp = B_proj[k];
    const float2 C2v = make_float2(2.f * bp * (num.x * re + num.y * im) * inv,
                                   2.f * bp * (num.y * re - num.x * im) * inv);

    // ---- combine carries of chunks 0..c-1 (L2-resident), grouped by 4 ----
    const float4* cp = carries + (size_t)(b * NC) * 256 + tid;
    float2 x0 = {0.f, 0.f}, x1 = {0.f, 0.f};
    int j = 0;
    for (; j + 4 <= c; j += 4) {
        float4 s0 = cp[(size_t)(j + 0) * 256];
        float4 s1 = cp[(size_t)(j + 1) * 256];
        float4 s2 = cp[(size_t)(j + 2) * 256];
        float4 s3 = cp[(size_t)(j + 3) * 256];
        float2 a0 = cadd(cmul(Act3, make_float2(s0.x, s0.y)), cmul(Act2, make_float2(s1.x, s1.y)));
        float2 a1 = cadd(cmul(Act,  make_float2(s2.x, s2.y)), make_float2(s3.x, s3.y));
        x0 = cadd(cmul(Act4, x0), cadd(a0, a1));
        float2 b0 = cadd(cmul(Act3, make_float2(s0.z, s0.w)), cmul(Act2, make_float2(s1.z, s1.w)));
        float2 b1 = cadd(cmul(Act,  make_float2(s2.z, s2.w)), make_float2(s3.z, s3.w));
        x1 = cadd(cmul(Act4, x1), cadd(b0, b1));
    }
    for (; j < c; ++j) {
        float4 s = cp[(size_t)j * 256];
        x0 = cadd(cmul(Act, x0), make_float2(s.x, s.y));
        x1 = cadd(cmul(Act, x1), make_float2(s.z, s.w));
    }

    // ---- replay chunk: two interleaved complex recurrences, float2 I/O ----
    const float2* hp = (const float2*)(h + ((size_t)b * T_LEN + (size_t)c * CT) * D_DIM) + d2;
    float2* op = (float2*)(out + (((size_t)b * T_LEN + (size_t)c * CT) * K_CH + k) * D_DIM) + d2;

    #pragma unroll
    for (int t = 0; t < CT; ++t) {
        float2 hv = hp[(size_t)t * (D_DIM / 2)];
        x0 = cmul(A, x0); x0.x += hv.x;
        x1 = cmul(A, x1); x1.x += hv.y;
        op[(size_t)t * (K_CH * D_DIM / 2)] =
            make_float2(C2v.x * x0.x - C2v.y * x0.y,
                        C2v.x * x1.x - C2v.y * x1.y);   // 8B/lane coalesced
    }
}

extern "C" void kernel_launch(void* const* d_in, const int* in_sizes, int n_in,
                              void* d_out, int out_size, void* d_ws, size_t ws_size,
                              hipStream_t stream) {
    const float* h          = (const float*)d_in[0];
    const float* log_neg_re = (const float*)d_in[1];
    const float* imag       = (const float*)d_in[2];
    const float* B_proj     = (const float*)d_in[3];
    const float* log_dt     = (const float*)d_in[4];
    float* out = (float*)d_out;

    float4* carries = (float4*)d_ws;   // NBLK * 4KB = 2 MiB

    hipLaunchKernelGGL(s4d_carry, dim3(NBLK), dim3(256), 0, stream,
                       h, log_neg_re, imag, log_dt, carries);
    hipLaunchKernelGGL(s4d_out, dim3(NBLK), dim3(256), 0, stream,
                       h, log_neg_re, imag, B_proj, log_dt, carries, out);
}